// Round 18
// baseline (637.247 us; speedup 1.0000x reference)
//
#include <hip/hip_runtime.h>
#include <stdint.h>

// Problem constants
constexpr int ROWS = 64;
constexpr int D = 1 << 19;             // 524288 per row
constexpr uint32_t KSEL = 52428;       // int(0.1 * D)
constexpr int MBPR = 32;               // blocks per row, cand_scan
constexpr int MCHUNK = D / MBPR;       // 16384 elements per block
constexpr int LBUF = 896;              // per-block slot cap (expected ~352, +29 sigma)
constexpr uint32_t PRED_B = 0xBFAu;    // key bucket of floats [1.25, 1.375)
constexpr uint32_t NCAND_MAX = 12288;  // per-row candidate cap (expected ~11.3K)

// mask_final geometry: 8 uint4 per thread, fully unrolled batch
constexpr int FBPR = 64;               // mask blocks per row
constexpr int FCHUNK_V4 = (D / 4) / FBPR;  // 2048 uint4 per block

// Workspace layout (u32 words). cnt/ovf are zeroed by select_thr at END of
// each call (self-healing: a poisoned first replay fails validity -> exact
// fallback -> zeroed for subsequent replays). Everything else plain-stored.
constexpr size_t OFF_ACNT = 0;                    // [2048] per-block above counts
constexpr size_t OFF_CNT  = 2048;                 // [64] per-row candidate count
constexpr size_t OFF_OVF  = OFF_CNT + 64;         // [64] per-row overflow flag
constexpr size_t OFF_THR  = OFF_OVF + 64;         // [64] threshold key per row
constexpr size_t OFF_CKEY = OFF_THR + 64;         // [64][NCAND_MAX] compact keys

typedef float f32x4 __attribute__((ext_vector_type(4)));

__device__ __forceinline__ uint32_t mono(uint32_t f) {
    uint32_t m = (uint32_t)((int32_t)f >> 31) | 0x80000000u;
    return f ^ m;
}

// Kernel 1 (read-only): candidate KEYS (bucket == PRED_B) -> per-row compact
// global array (one global atomic per block); per-block above-bucket count.
__global__ __launch_bounds__(256) void cand_scan(const uint32_t* __restrict__ x,
                                                 uint32_t* __restrict__ ws) {
    __shared__ uint32_t lkey[LBUF];
    __shared__ uint32_t red[256];
    __shared__ uint32_t ln, gbase;
    if (threadIdx.x == 0) ln = 0;
    __syncthreads();
    const int bid = blockIdx.x;
    const int row = bid / MBPR, chunk = bid % MBPR, t = threadIdx.x;
    const uint4* __restrict__ p = (const uint4*)(x + (size_t)row * D + (size_t)chunk * MCHUNK);
    uint32_t above = 0;
    for (int i = t; i < MCHUNK / 4; i += 256) {
        uint4 v = p[i];
#define CLS(comp)                                                          \
        {                                                                  \
            uint32_t u = mono(comp);                                       \
            uint32_t bu = u >> 20;                                         \
            above += (bu > PRED_B);                                        \
            if (bu == PRED_B) {                                            \
                uint32_t s = atomicAdd(&ln, 1u);                           \
                if (s < (uint32_t)LBUF) lkey[s] = u;                       \
            }                                                              \
        }
        CLS(v.x) CLS(v.y) CLS(v.z) CLS(v.w)
#undef CLS
    }
    red[t] = above;
    __syncthreads();
    for (int off = 128; off > 0; off >>= 1) {
        if (t < off) red[t] += red[t + off];
        __syncthreads();
    }
    uint32_t m = ln < (uint32_t)LBUF ? ln : (uint32_t)LBUF;
    if (t == 0) {
        ws[OFF_ACNT + bid] = red[0];
        gbase = atomicAdd(&ws[OFF_CNT + row], m);
        if (ln > (uint32_t)LBUF) atomicOr(&ws[OFF_OVF + row], 1u);
    }
    __syncthreads();
    uint32_t base = gbase;
    uint32_t* ck = ws + OFF_CKEY + (size_t)row * NCAND_MAX;
    for (uint32_t i = t; i < m; i += 256) {
        uint32_t slot = base + i;
        if (slot < NCAND_MAX) ck[slot] = lkey[i];
    }
}

// Kernel 2, one block per row: exact threshold key. Valid path: flat
// pipelined gather of the compact key array -> two-level radix select
// (rank = KSEL - above). Invalid (poison/overflow/misprediction): exact
// 3-pass histogram select over the row. Zeroes cnt/ovf for the next call.
__global__ __launch_bounds__(256) void select_thr(const uint32_t* __restrict__ x,
                                                  uint32_t* __restrict__ ws) {
    __shared__ uint32_t ckey[NCAND_MAX];  // 48 KB; fallback reuses [0..4096) as hist
    __shared__ uint32_t h[1024];
    __shared__ uint32_t sc[256];
    __shared__ uint32_t bc[3];
    const int row = blockIdx.x, t = threadIdx.x;

    // parallel above-count reduction over the row's 32 block counts
    sc[t] = (t < MBPR) ? ws[OFF_ACNT + (size_t)row * MBPR + t] : 0u;
    __syncthreads();
    for (int off = 128; off > 0; off >>= 1) {
        if (t < off) sc[t] += sc[t + off];
        __syncthreads();
    }
    const uint32_t above = sc[0];
    const uint32_t n_raw = ws[OFF_CNT + row];
    const uint32_t ovf = ws[OFF_OVF + row];
    const bool valid = (ovf == 0u && n_raw <= NCAND_MAX &&
                        above < KSEL && above + n_raw >= KSEL);
    __syncthreads();

    if (valid) {
        const uint32_t n = n_raw;
        const uint32_t k = KSEL - above;  // rank among candidates, 1-based
        const uint32_t* ck = ws + OFF_CKEY + (size_t)row * NCAND_MAX;
        // flat pipelined gather (no serial segments)
        for (uint32_t i = t; i < n; i += 256) ckey[i] = ck[i];
        // Level 1: bits 19..10
        for (int i = t; i < 1024; i += 256) h[i] = 0;
        __syncthreads();
        for (uint32_t i = t; i < n; i += 256) atomicAdd(&h[(ckey[i] >> 10) & 0x3FFu], 1u);
        __syncthreads();
        {
            int hi = 1023 - t * 4;
            uint32_t s = 0;
            for (int j = 0; j < 4; ++j) s += h[hi - j];
            sc[t] = s;
            __syncthreads();
            for (int off = 1; off < 256; off <<= 1) {
                uint32_t v = (t >= off) ? sc[t - off] : 0u;
                __syncthreads();
                sc[t] += v;
                __syncthreads();
            }
            uint32_t excl = sc[t] - s;
            if (excl < k && excl + s >= k) {
                uint32_t cc = excl;
                for (int j = 0; j < 4; ++j) {
                    int bin = hi - j;
                    uint32_t hb = h[bin];
                    cc += hb;
                    if (cc >= k) { bc[0] = (uint32_t)bin; bc[1] = k - (cc - hb); break; }
                }
            }
        }
        __syncthreads();
        uint32_t b1 = bc[0], k2 = bc[1];
        __syncthreads();
        // Level 2: bits 9..0
        for (int i = t; i < 1024; i += 256) h[i] = 0;
        __syncthreads();
        for (uint32_t i = t; i < n; i += 256) {
            uint32_t u = ckey[i];
            if (((u >> 10) & 0x3FFu) == b1) atomicAdd(&h[u & 0x3FFu], 1u);
        }
        __syncthreads();
        {
            int hi = 1023 - t * 4;
            uint32_t s = 0;
            for (int j = 0; j < 4; ++j) s += h[hi - j];
            sc[t] = s;
            __syncthreads();
            for (int off = 1; off < 256; off <<= 1) {
                uint32_t v = (t >= off) ? sc[t - off] : 0u;
                __syncthreads();
                sc[t] += v;
                __syncthreads();
            }
            uint32_t excl = sc[t] - s;
            if (excl < k2 && excl + s >= k2) {
                uint32_t cc = excl;
                for (int j = 0; j < 4; ++j) {
                    int bin = hi - j;
                    uint32_t hb = h[bin];
                    cc += hb;
                    if (cc >= k2) {
                        ws[OFF_THR + row] = (PRED_B << 20) | (b1 << 10) | (uint32_t)bin;
                        break;
                    }
                }
            }
        }
        if (t == 0) { ws[OFF_CNT + row] = 0u; ws[OFF_OVF + row] = 0u; }
        return;
    }

    // ---------- exact fallback (any-data correct) ----------
    const uint4* px = (const uint4*)(x + (size_t)row * D);
    uint32_t* h4k = ckey;  // reuse 16 KB of ckey as 4096-bin hist

    for (int i = t; i < 4096; i += 256) h4k[i] = 0;
    __syncthreads();
    for (int i = t; i < D / 4; i += 256) {
        uint4 v = px[i];
        atomicAdd(&h4k[mono(v.x) >> 20], 1u);
        atomicAdd(&h4k[mono(v.y) >> 20], 1u);
        atomicAdd(&h4k[mono(v.z) >> 20], 1u);
        atomicAdd(&h4k[mono(v.w) >> 20], 1u);
    }
    __syncthreads();
    {
        int hi = 4095 - t * 16;
        uint32_t loc[16];
        uint32_t s = 0;
#pragma unroll
        for (int j = 0; j < 16; ++j) { loc[j] = h4k[hi - j]; s += loc[j]; }
        sc[t] = s;
        __syncthreads();
        for (int off = 1; off < 256; off <<= 1) {
            uint32_t v = (t >= off) ? sc[t - off] : 0u;
            __syncthreads();
            sc[t] += v;
            __syncthreads();
        }
        uint32_t excl = sc[t] - s;
        if (excl < KSEL && excl + s >= KSEL) {
            uint32_t c = excl;
            for (int j = 0; j < 16; ++j) {
                c += loc[j];
                if (c >= KSEL) { bc[0] = (uint32_t)(hi - j); bc[1] = KSEL - (c - loc[j]); break; }
            }
        }
    }
    __syncthreads();
    const uint32_t B = bc[0], r1 = bc[1];
    __syncthreads();

    for (int i = t; i < 1024; i += 256) h[i] = 0;
    __syncthreads();
    for (int i = t; i < D / 4; i += 256) {
        uint4 v = px[i];
        uint32_t u;
        u = mono(v.x); if ((u >> 20) == B) atomicAdd(&h[(u >> 10) & 0x3FFu], 1u);
        u = mono(v.y); if ((u >> 20) == B) atomicAdd(&h[(u >> 10) & 0x3FFu], 1u);
        u = mono(v.z); if ((u >> 20) == B) atomicAdd(&h[(u >> 10) & 0x3FFu], 1u);
        u = mono(v.w); if ((u >> 20) == B) atomicAdd(&h[(u >> 10) & 0x3FFu], 1u);
    }
    __syncthreads();
    {
        int hi = 1023 - t * 4;
        uint32_t s = 0;
        for (int j = 0; j < 4; ++j) s += h[hi - j];
        sc[t] = s;
        __syncthreads();
        for (int off = 1; off < 256; off <<= 1) {
            uint32_t v = (t >= off) ? sc[t - off] : 0u;
            __syncthreads();
            sc[t] += v;
            __syncthreads();
        }
        uint32_t excl = sc[t] - s;
        if (excl < r1 && excl + s >= r1) {
            uint32_t cc = excl;
            for (int j = 0; j < 4; ++j) {
                int bin = hi - j;
                uint32_t hb = h[bin];
                cc += hb;
                if (cc >= r1) { bc[0] = (uint32_t)bin; bc[1] = r1 - (cc - hb); break; }
            }
        }
    }
    __syncthreads();
    const uint32_t pref22 = (B << 10) | bc[0];
    const uint32_t r2 = bc[1];
    __syncthreads();

    for (int i = t; i < 1024; i += 256) h[i] = 0;
    __syncthreads();
    for (int i = t; i < D / 4; i += 256) {
        uint4 v = px[i];
        uint32_t u;
        u = mono(v.x); if ((u >> 10) == pref22) atomicAdd(&h[u & 0x3FFu], 1u);
        u = mono(v.y); if ((u >> 10) == pref22) atomicAdd(&h[u & 0x3FFu], 1u);
        u = mono(v.z); if ((u >> 10) == pref22) atomicAdd(&h[u & 0x3FFu], 1u);
        u = mono(v.w); if ((u >> 10) == pref22) atomicAdd(&h[u & 0x3FFu], 1u);
    }
    __syncthreads();
    {
        int hi = 1023 - t * 4;
        uint32_t s = 0;
        for (int j = 0; j < 4; ++j) s += h[hi - j];
        sc[t] = s;
        __syncthreads();
        for (int off = 1; off < 256; off <<= 1) {
            uint32_t v = (t >= off) ? sc[t - off] : 0u;
            __syncthreads();
            sc[t] += v;
            __syncthreads();
        }
        uint32_t excl = sc[t] - s;
        if (excl < r2 && excl + s >= r2) {
            uint32_t cc = excl;
            for (int j = 0; j < 4; ++j) {
                int bin = hi - j;
                uint32_t hb = h[bin];
                cc += hb;
                if (cc >= r2) { ws[OFF_THR + row] = (pref22 << 10) | (uint32_t)bin; break; }
            }
        }
    }
    if (t == 0) { ws[OFF_CNT + row] = 0u; ws[OFF_OVF + row] = 0u; }
}

// Kernel 3: streaming masked copy, 8-deep MLP batch, NT stores.
__global__ __launch_bounds__(256) void mask_final(const uint32_t* __restrict__ x,
                                                  float* __restrict__ out,
                                                  const uint32_t* __restrict__ ws) {
    const int bid = blockIdx.x;                 // 4096 blocks
    const int row = bid / FBPR, chunk = bid % FBPR, t = threadIdx.x;
    const uint32_t tk = ws[OFF_THR + row];
    const uint4* __restrict__ p =
        (const uint4*)(x + (size_t)row * D) + (size_t)chunk * FCHUNK_V4;
    f32x4* __restrict__ o =
        (f32x4*)(out + (size_t)row * D) + (size_t)chunk * FCHUNK_V4;

    uint4 v[8];
#pragma unroll
    for (int k = 0; k < 8; ++k) v[k] = p[t + k * 256];   // 8 loads in flight
    f32x4 ov[8];
#pragma unroll
    for (int k = 0; k < 8; ++k) {
        ov[k][0] = (mono(v[k].x) < tk) ? __uint_as_float(v[k].x) : 0.0f;
        ov[k][1] = (mono(v[k].y) < tk) ? __uint_as_float(v[k].y) : 0.0f;
        ov[k][2] = (mono(v[k].z) < tk) ? __uint_as_float(v[k].z) : 0.0f;
        ov[k][3] = (mono(v[k].w) < tk) ? __uint_as_float(v[k].w) : 0.0f;
    }
#pragma unroll
    for (int k = 0; k < 8; ++k)
        __builtin_nontemporal_store(ov[k], &o[t + k * 256]);
}

extern "C" void kernel_launch(void* const* d_in, const int* in_sizes, int n_in,
                              void* d_out, int out_size, void* d_ws, size_t ws_size,
                              hipStream_t stream) {
    (void)in_sizes; (void)n_in; (void)out_size; (void)ws_size;
    const uint32_t* xu = (const uint32_t*)d_in[0];
    float* outp = (float*)d_out;
    uint32_t* ws = (uint32_t*)d_ws;

    cand_scan<<<ROWS * MBPR, 256, 0, stream>>>(xu, ws);
    select_thr<<<ROWS, 256, 0, stream>>>(xu, ws);
    mask_final<<<ROWS * FBPR, 256, 0, stream>>>(xu, outp, ws);
}

// Round 19
// 122.350 us; speedup vs baseline: 5.2084x; 5.2084x over previous
//
#include <hip/hip_runtime.h>
#include <stdint.h>

// Problem constants
constexpr int ROWS = 64;
constexpr int D = 1 << 19;             // 524288 per row
constexpr uint32_t KSEL = 52428;       // int(0.1 * D)
constexpr int BPR = 32;                // blocks per row (both kernels)
constexpr int CHUNK = D / BPR;         // 16384 elements per block
constexpr int LBUF = 896;              // per-block key cap (expected ~352, +29 sigma)
constexpr uint32_t PRED_B = 0xBFAu;    // key bucket of floats [1.25, 1.375);
                                       // K-th largest = 1.2816 +- 0.0024 (13/39 sigma)

// Workspace layout (u32 words) — ALL state plain-stored fresh every call
// before it is read (no accumulation, no zeroing, no cross-call state).
constexpr size_t OFF_SCNT = 0;                    // [2048] per-block candidate count
constexpr size_t OFF_ACNT = 2048;                 // [2048] per-block above count
constexpr size_t OFF_KEYS = 4096;                 // [2048][LBUF] candidate keys

typedef float f32x4 __attribute__((ext_vector_type(4)));

__device__ __forceinline__ uint32_t mono(uint32_t f) {
    uint32_t m = (uint32_t)((int32_t)f >> 31) | 0x80000000u;
    return f ^ m;
}

// Kernel 1 (read-only over x): per-block candidate KEYS (bucket == PRED_B)
// into private segment + per-block above-bucket count. Stateless: every
// output word overwritten each call.
__global__ __launch_bounds__(256) void cand_scan(const uint32_t* __restrict__ x,
                                                 uint32_t* __restrict__ ws) {
    __shared__ uint32_t lkey[LBUF];
    __shared__ uint32_t red[256];
    __shared__ uint32_t ln;
    if (threadIdx.x == 0) ln = 0;
    __syncthreads();
    const int bid = blockIdx.x;
    const int row = bid / BPR, chunk = bid % BPR, t = threadIdx.x;
    const uint4* __restrict__ p = (const uint4*)(x + (size_t)row * D + (size_t)chunk * CHUNK);
    uint32_t above = 0;
    for (int i = t; i < CHUNK / 4; i += 256) {
        uint4 v = p[i];
#define CLS(comp)                                                          \
        {                                                                  \
            uint32_t u = mono(comp);                                       \
            uint32_t bu = u >> 20;                                         \
            above += (bu > PRED_B);                                        \
            if (bu == PRED_B) {                                            \
                uint32_t s = atomicAdd(&ln, 1u);                           \
                if (s < (uint32_t)LBUF) lkey[s] = u;                       \
            }                                                              \
        }
        CLS(v.x) CLS(v.y) CLS(v.z) CLS(v.w)
#undef CLS
    }
    red[t] = above;
    __syncthreads();
    for (int off = 128; off > 0; off >>= 1) {
        if (t < off) red[t] += red[t + off];
        __syncthreads();
    }
    if (t == 0) {
        ws[OFF_SCNT + bid] = ln;       // raw count; > LBUF signals overflow
        ws[OFF_ACNT + bid] = red[0];
    }
    uint32_t m = ln < (uint32_t)LBUF ? ln : (uint32_t)LBUF;
    uint32_t* sk = ws + OFF_KEYS + (size_t)bid * LBUF;
    for (uint32_t i = t; i < m; i += 256) sk[i] = lkey[i];
}

// Kernel 2: fused select + mask. 2048 blocks, 8 co-resident blocks/CU.
// Each block redundantly computes its row's exact threshold key (parallel
// count-reduce, then two-level radix streaming the row's 32 key segments
// from L2), then streams its mask chunk (8-deep MLP batches, NT stores).
// All inputs were plain-stored THIS call -> poison-immune; fallback only
// on genuine misprediction (exact 3-pass histogram select over the row).
__global__ __launch_bounds__(256) void mask_sel(const uint32_t* __restrict__ x,
                                                float* __restrict__ out,
                                                const uint32_t* __restrict__ ws) {
    __shared__ uint32_t h[1024];
    __shared__ uint32_t sc[256];
    __shared__ uint32_t cnts[BPR];
    __shared__ uint32_t bc[2];
    const int bid = blockIdx.x;
    const int row = bid / BPR, chunk = bid % BPR, t = threadIdx.x;

    // ---- per-row totals from per-block stats (parallel) ----
    uint32_t myc = 0, mya = 0;
    if (t < BPR) {
        myc = ws[OFF_SCNT + (size_t)row * BPR + t];
        mya = ws[OFF_ACNT + (size_t)row * BPR + t];
        cnts[t] = myc;
    }
    sc[t] = (t < BPR) ? ((myc > (uint32_t)LBUF ? 0x40000000u : 0u) + myc) : 0u;
    __syncthreads();
    // reduce candidate-count (+overflow flag in high bits)
    for (int off = 128; off > 0; off >>= 1) {
        if (t < off) sc[t] += sc[t + off];
        __syncthreads();
    }
    const uint32_t ntot_f = sc[0];
    __syncthreads();
    sc[t] = (t < BPR) ? mya : 0u;
    __syncthreads();
    for (int off = 128; off > 0; off >>= 1) {
        if (t < off) sc[t] += sc[t + off];
        __syncthreads();
    }
    const uint32_t above = sc[0];
    const uint32_t n = ntot_f & 0x3FFFFFFFu;
    const bool valid = ((ntot_f & 0xC0000000u) == 0u) &&
                       (above < KSEL) && (above + n >= KSEL);
    __syncthreads();

    uint32_t thr_key;
    if (valid) {
        const uint32_t k = KSEL - above;  // rank among candidates, 1-based
        const uint32_t* keys0 = ws + OFF_KEYS + (size_t)row * BPR * LBUF;

        // Level 1: bits 19..10 (stream segments; LDS-privatized histogram)
        for (int i = t; i < 1024; i += 256) h[i] = 0;
        __syncthreads();
        for (int s = 0; s < BPR; ++s) {
            uint32_t c = cnts[s];
            const uint32_t* sk = keys0 + (size_t)s * LBUF;
            for (uint32_t i = t; i < c; i += 256)
                atomicAdd(&h[(sk[i] >> 10) & 0x3FFu], 1u);
        }
        __syncthreads();
        {
            int hi = 1023 - t * 4;
            uint32_t s = 0;
            for (int j = 0; j < 4; ++j) s += h[hi - j];
            sc[t] = s;
            __syncthreads();
            for (int off = 1; off < 256; off <<= 1) {
                uint32_t v = (t >= off) ? sc[t - off] : 0u;
                __syncthreads();
                sc[t] += v;
                __syncthreads();
            }
            uint32_t excl = sc[t] - s;
            if (excl < k && excl + s >= k) {
                uint32_t cc = excl;
                for (int j = 0; j < 4; ++j) {
                    int bin = hi - j;
                    uint32_t hb = h[bin];
                    cc += hb;
                    if (cc >= k) { bc[0] = (uint32_t)bin; bc[1] = k - (cc - hb); break; }
                }
            }
        }
        __syncthreads();
        const uint32_t b1 = bc[0], k2 = bc[1];
        __syncthreads();

        // Level 2: bits 9..0 among candidates matching b1
        for (int i = t; i < 1024; i += 256) h[i] = 0;
        __syncthreads();
        for (int s = 0; s < BPR; ++s) {
            uint32_t c = cnts[s];
            const uint32_t* sk = keys0 + (size_t)s * LBUF;
            for (uint32_t i = t; i < c; i += 256) {
                uint32_t u = sk[i];
                if (((u >> 10) & 0x3FFu) == b1) atomicAdd(&h[u & 0x3FFu], 1u);
            }
        }
        __syncthreads();
        {
            int hi = 1023 - t * 4;
            uint32_t s = 0;
            for (int j = 0; j < 4; ++j) s += h[hi - j];
            sc[t] = s;
            __syncthreads();
            for (int off = 1; off < 256; off <<= 1) {
                uint32_t v = (t >= off) ? sc[t - off] : 0u;
                __syncthreads();
                sc[t] += v;
                __syncthreads();
            }
            uint32_t excl = sc[t] - s;
            if (excl < k2 && excl + s >= k2) {
                uint32_t cc = excl;
                for (int j = 0; j < 4; ++j) {
                    int bin = hi - j;
                    uint32_t hb = h[bin];
                    cc += hb;
                    if (cc >= k2) { bc[0] = (PRED_B << 20) | (b1 << 10) | (uint32_t)bin; break; }
                }
            }
        }
        __syncthreads();
        thr_key = bc[0];
    } else {
        // ---- exact fallback: 3-pass histogram select over the row ----
        // (only on genuine misprediction; 32x redundant but correct)
        const uint4* px = (const uint4*)(x + (size_t)row * D);
        __syncthreads();
        // Pass A: 1024-bin hist of top 10 key bits -> coarse bucket + rank
        for (int i = t; i < 1024; i += 256) h[i] = 0;
        __syncthreads();
        for (int i = t; i < D / 4; i += 256) {
            uint4 v = px[i];
            atomicAdd(&h[mono(v.x) >> 22], 1u);
            atomicAdd(&h[mono(v.y) >> 22], 1u);
            atomicAdd(&h[mono(v.z) >> 22], 1u);
            atomicAdd(&h[mono(v.w) >> 22], 1u);
        }
        __syncthreads();
        {
            int hi = 1023 - t * 4;
            uint32_t s = 0;
            for (int j = 0; j < 4; ++j) s += h[hi - j];
            sc[t] = s;
            __syncthreads();
            for (int off = 1; off < 256; off <<= 1) {
                uint32_t v = (t >= off) ? sc[t - off] : 0u;
                __syncthreads();
                sc[t] += v;
                __syncthreads();
            }
            uint32_t excl = sc[t] - s;
            if (excl < KSEL && excl + s >= KSEL) {
                uint32_t cc = excl;
                for (int j = 0; j < 4; ++j) {
                    int bin = hi - j;
                    uint32_t hb = h[bin];
                    cc += hb;
                    if (cc >= KSEL) { bc[0] = (uint32_t)bin; bc[1] = KSEL - (cc - hb); break; }
                }
            }
        }
        __syncthreads();
        const uint32_t B10 = bc[0], r1 = bc[1];
        __syncthreads();
        // Pass B: bits 21..11 (11 bits -> 2048? keep 1024: bits 21..12) ...
        // use bits 21..12 (10 bits) among bucket == B10
        for (int i = t; i < 1024; i += 256) h[i] = 0;
        __syncthreads();
        for (int i = t; i < D / 4; i += 256) {
            uint4 v = px[i];
            uint32_t u;
            u = mono(v.x); if ((u >> 22) == B10) atomicAdd(&h[(u >> 12) & 0x3FFu], 1u);
            u = mono(v.y); if ((u >> 22) == B10) atomicAdd(&h[(u >> 12) & 0x3FFu], 1u);
            u = mono(v.z); if ((u >> 22) == B10) atomicAdd(&h[(u >> 12) & 0x3FFu], 1u);
            u = mono(v.w); if ((u >> 22) == B10) atomicAdd(&h[(u >> 12) & 0x3FFu], 1u);
        }
        __syncthreads();
        {
            int hi = 1023 - t * 4;
            uint32_t s = 0;
            for (int j = 0; j < 4; ++j) s += h[hi - j];
            sc[t] = s;
            __syncthreads();
            for (int off = 1; off < 256; off <<= 1) {
                uint32_t v = (t >= off) ? sc[t - off] : 0u;
                __syncthreads();
                sc[t] += v;
                __syncthreads();
            }
            uint32_t excl = sc[t] - s;
            if (excl < r1 && excl + s >= r1) {
                uint32_t cc = excl;
                for (int j = 0; j < 4; ++j) {
                    int bin = hi - j;
                    uint32_t hb = h[bin];
                    cc += hb;
                    if (cc >= r1) { bc[0] = (uint32_t)bin; bc[1] = r1 - (cc - hb); break; }
                }
            }
        }
        __syncthreads();
        const uint32_t pref20 = (B10 << 10) | bc[0];  // top 20 bits
        const uint32_t r2 = bc[1];
        __syncthreads();
        // Pass C: low 12 bits among (u >> 12) == pref20 (4096 bins in h+sc? )
        // use two 1024-bin rounds: bits 11..2 then exact among <=4 remaining
        // Simpler: 12-bit via 1024 bins on bits 11..2, then resolve last 2
        // bits exactly by counting (few keys). For simplicity: bits 11..2.
        for (int i = t; i < 1024; i += 256) h[i] = 0;
        __syncthreads();
        for (int i = t; i < D / 4; i += 256) {
            uint4 v = px[i];
            uint32_t u;
            u = mono(v.x); if ((u >> 12) == pref20) atomicAdd(&h[(u >> 2) & 0x3FFu], 1u);
            u = mono(v.y); if ((u >> 12) == pref20) atomicAdd(&h[(u >> 2) & 0x3FFu], 1u);
            u = mono(v.z); if ((u >> 12) == pref20) atomicAdd(&h[(u >> 2) & 0x3FFu], 1u);
            u = mono(v.w); if ((u >> 12) == pref20) atomicAdd(&h[(u >> 2) & 0x3FFu], 1u);
        }
        __syncthreads();
        {
            int hi = 1023 - t * 4;
            uint32_t s = 0;
            for (int j = 0; j < 4; ++j) s += h[hi - j];
            sc[t] = s;
            __syncthreads();
            for (int off = 1; off < 256; off <<= 1) {
                uint32_t v = (t >= off) ? sc[t - off] : 0u;
                __syncthreads();
                sc[t] += v;
                __syncthreads();
            }
            uint32_t excl = sc[t] - s;
            if (excl < r2 && excl + s >= r2) {
                uint32_t cc = excl;
                for (int j = 0; j < 4; ++j) {
                    int bin = hi - j;
                    uint32_t hb = h[bin];
                    cc += hb;
                    if (cc >= r2) { bc[0] = (pref20 << 12) | ((uint32_t)bin << 2); bc[1] = r2 - (cc - hb); break; }
                }
            }
        }
        __syncthreads();
        const uint32_t pref30 = bc[0] >> 2;  // top 30 bits
        const uint32_t r3 = bc[1];
        __syncthreads();
        // Pass D: resolve final 2 bits exactly (4 bins)
        if (t < 4) h[t] = 0;
        __syncthreads();
        for (int i = t; i < D / 4; i += 256) {
            uint4 v = px[i];
            uint32_t u;
            u = mono(v.x); if ((u >> 2) == pref30) atomicAdd(&h[u & 3u], 1u);
            u = mono(v.y); if ((u >> 2) == pref30) atomicAdd(&h[u & 3u], 1u);
            u = mono(v.z); if ((u >> 2) == pref30) atomicAdd(&h[u & 3u], 1u);
            u = mono(v.w); if ((u >> 2) == pref30) atomicAdd(&h[u & 3u], 1u);
        }
        __syncthreads();
        if (t == 0) {
            uint32_t cc = 0;
            for (int b = 3; b >= 0; --b) {
                cc += h[b];
                if (cc >= r3) { bc[0] = (pref30 << 2) | (uint32_t)b; break; }
            }
        }
        __syncthreads();
        thr_key = bc[0];
    }

    // ---- mask this block's chunk: 2 x 8-deep MLP batches, NT stores ----
    const uint32_t tk = thr_key;
    const uint4* __restrict__ p =
        (const uint4*)(x + (size_t)row * D) + (size_t)chunk * (CHUNK / 4);
    f32x4* __restrict__ o =
        (f32x4*)(out + (size_t)row * D) + (size_t)chunk * (CHUNK / 4);
#pragma unroll 1
    for (int half = 0; half < 2; ++half) {
        const int base = half * 2048 + t;
        uint4 v[8];
#pragma unroll
        for (int q = 0; q < 8; ++q) v[q] = p[base + q * 256];
        f32x4 ov[8];
#pragma unroll
        for (int q = 0; q < 8; ++q) {
            ov[q][0] = (mono(v[q].x) < tk) ? __uint_as_float(v[q].x) : 0.0f;
            ov[q][1] = (mono(v[q].y) < tk) ? __uint_as_float(v[q].y) : 0.0f;
            ov[q][2] = (mono(v[q].z) < tk) ? __uint_as_float(v[q].z) : 0.0f;
            ov[q][3] = (mono(v[q].w) < tk) ? __uint_as_float(v[q].w) : 0.0f;
        }
#pragma unroll
        for (int q = 0; q < 8; ++q)
            __builtin_nontemporal_store(ov[q], &o[base + q * 256]);
    }
}

extern "C" void kernel_launch(void* const* d_in, const int* in_sizes, int n_in,
                              void* d_out, int out_size, void* d_ws, size_t ws_size,
                              hipStream_t stream) {
    (void)in_sizes; (void)n_in; (void)out_size; (void)ws_size;
    const uint32_t* xu = (const uint32_t*)d_in[0];
    float* outp = (float*)d_out;
    uint32_t* ws = (uint32_t*)d_ws;

    cand_scan<<<ROWS * BPR, 256, 0, stream>>>(xu, ws);
    mask_sel<<<ROWS * BPR, 256, 0, stream>>>(xu, outp, ws);
}

// Round 20
// 95.537 us; speedup vs baseline: 6.6702x; 1.2807x over previous
//
#include <hip/hip_runtime.h>
#include <stdint.h>

// Problem constants
constexpr int ROWS = 64;
constexpr int D = 1 << 19;             // 524288 per row
constexpr uint32_t KSEL = 52428;       // int(0.1 * D)
constexpr int BPR = 32;                // blocks per row, cand_scan
constexpr int CHUNK = D / BPR;         // 16384 elements per block
constexpr int LBUF = 896;              // per-block key cap (expected ~352, +29 sigma)
constexpr uint32_t PRED_B = 0xBFAu;    // key bucket of floats [1.25, 1.375);
                                       // K-th largest = 1.2816 +- 0.0024 (13/39 sigma)

// mask_final geometry: 8 uint4 per thread, fully unrolled batch
constexpr int FBPR = 64;               // mask blocks per row
constexpr int FCHUNK_V4 = (D / 4) / FBPR;  // 2048 uint4 per block

// Workspace layout (u32 words) — ALL state plain-stored fresh every call
// before it is read (no accumulation, no zeroing, no cross-call state).
constexpr size_t OFF_SCNT  = 0;                        // [2048] per-block raw cand count
constexpr size_t OFF_ACNT  = 2048;                     // [2048] per-block above count
constexpr size_t OFF_THR   = 4096;                     // [64] threshold key per row
constexpr size_t OFF_CHIST = 4160;                     // [2048][512] u16-packed 1024-bin hist
constexpr size_t OFF_KEYS  = OFF_CHIST + 2048 * 512;   // [2048][LBUF] candidate keys

typedef float f32x4 __attribute__((ext_vector_type(4)));

__device__ __forceinline__ uint32_t mono(uint32_t f) {
    uint32_t m = (uint32_t)((int32_t)f >> 31) | 0x80000000u;
    return f ^ m;
}

// Kernel 1 (read-only over x): per-block candidate KEYS + per-block
// 1024-bin partial histogram of candidate bits 19..10 (packed u16) +
// above-bucket count. Stateless: every output word overwritten each call.
__global__ __launch_bounds__(256) void cand_scan(const uint32_t* __restrict__ x,
                                                 uint32_t* __restrict__ ws) {
    __shared__ uint32_t lkey[LBUF];
    __shared__ uint32_t h1[1024];
    __shared__ uint32_t red[256];
    __shared__ uint32_t ln;
    for (int i = threadIdx.x; i < 1024; i += 256) h1[i] = 0;
    if (threadIdx.x == 0) ln = 0;
    __syncthreads();
    const int bid = blockIdx.x;
    const int row = bid / BPR, chunk = bid % BPR, t = threadIdx.x;
    const uint4* __restrict__ p = (const uint4*)(x + (size_t)row * D + (size_t)chunk * CHUNK);
    uint32_t above = 0;
    for (int i = t; i < CHUNK / 4; i += 256) {
        uint4 v = p[i];
#define CLS(comp)                                                          \
        {                                                                  \
            uint32_t u = mono(comp);                                       \
            uint32_t bu = u >> 20;                                         \
            above += (bu > PRED_B);                                        \
            if (bu == PRED_B) {                                            \
                uint32_t s = atomicAdd(&ln, 1u);                           \
                if (s < (uint32_t)LBUF) lkey[s] = u;                       \
                atomicAdd(&h1[(u >> 10) & 0x3FFu], 1u);                    \
            }                                                              \
        }
        CLS(v.x) CLS(v.y) CLS(v.z) CLS(v.w)
#undef CLS
    }
    red[t] = above;
    __syncthreads();
    for (int off = 128; off > 0; off >>= 1) {
        if (t < off) red[t] += red[t + off];
        __syncthreads();
    }
    if (t == 0) {
        ws[OFF_SCNT + bid] = ln;       // raw count; > LBUF signals overflow
        ws[OFF_ACNT + bid] = red[0];
    }
    // pack 1024-bin hist -> 512 u32 (max count/bin <= 16384, fits u16)
    {
        uint32_t* ch = ws + OFF_CHIST + (size_t)bid * 512;
        for (int i = t; i < 512; i += 256)
            ch[i] = (h1[2 * i] & 0xFFFFu) | (h1[2 * i + 1] << 16);
    }
    uint32_t m = ln < (uint32_t)LBUF ? ln : (uint32_t)LBUF;
    uint32_t* sk = ws + OFF_KEYS + (size_t)bid * LBUF;
    for (uint32_t i = t; i < m; i += 256) sk[i] = lkey[i];
}

// Kernel 2, one block per row: exact threshold key, cheap.
// L1 (bits 19..10): reduce the 32 per-block packed hists (64 independent
// pipelined loads/thread) + suffix scan. L2 (bits 9..0): one flat coalesced
// stream of the key slots. Fallback (misprediction only, poison-immune):
// 4-pass 1024-bin histogram select over the full row.
__global__ __launch_bounds__(256) void select_thr(const uint32_t* __restrict__ x,
                                                  uint32_t* __restrict__ ws) {
    __shared__ uint32_t h[1024];
    __shared__ uint32_t sc[256];
    __shared__ uint32_t cnts[BPR];     // stored (capped) per-block counts
    __shared__ uint32_t bc[2];
    const int row = blockIdx.x, t = threadIdx.x;

    // per-row totals (parallel)
    uint32_t myc = 0, mya = 0;
    if (t < BPR) {
        myc = ws[OFF_SCNT + (size_t)row * BPR + t];
        mya = ws[OFF_ACNT + (size_t)row * BPR + t];
        cnts[t] = myc < (uint32_t)LBUF ? myc : (uint32_t)LBUF;
    }
    sc[t] = (t < BPR) ? ((myc > (uint32_t)LBUF ? 0x40000000u : 0u) + myc) : 0u;
    __syncthreads();
    for (int off = 128; off > 0; off >>= 1) {
        if (t < off) sc[t] += sc[t + off];
        __syncthreads();
    }
    const uint32_t ntot_f = sc[0];
    __syncthreads();
    sc[t] = (t < BPR) ? mya : 0u;
    __syncthreads();
    for (int off = 128; off > 0; off >>= 1) {
        if (t < off) sc[t] += sc[t + off];
        __syncthreads();
    }
    const uint32_t above = sc[0];
    const uint32_t n = ntot_f & 0x3FFFFFFFu;
    const bool valid = ((ntot_f & 0xC0000000u) == 0u) &&
                       (above < KSEL) && (above + n >= KSEL);
    __syncthreads();

    if (valid) {
        const uint32_t k = KSEL - above;  // rank among candidates, 1-based

        // ---- L1: reduce packed per-block hists; descending ownership ----
        // thread t owns bins [1020-4t .. 1023-4t]
        const int base_bin = 1020 - 4 * t;
        uint32_t acc[4] = {0, 0, 0, 0};
        const uint32_t* ch0 = ws + OFF_CHIST + (size_t)row * BPR * 512 + (base_bin >> 1);
#pragma unroll 4
        for (int s = 0; s < BPR; ++s) {
            uint32_t p0 = ch0[(size_t)s * 512];
            uint32_t p1 = ch0[(size_t)s * 512 + 1];
            acc[0] += p0 & 0xFFFFu; acc[1] += p0 >> 16;
            acc[2] += p1 & 0xFFFFu; acc[3] += p1 >> 16;
        }
        uint32_t s_sum = acc[0] + acc[1] + acc[2] + acc[3];
        sc[t] = s_sum;
        __syncthreads();
        for (int off = 1; off < 256; off <<= 1) {
            uint32_t v = (t >= off) ? sc[t - off] : 0u;
            __syncthreads();
            sc[t] += v;
            __syncthreads();
        }
        uint32_t excl = sc[t] - s_sum;   // count in bins strictly above my group
        if (excl < k && excl + s_sum >= k) {  // exactly one thread
            uint32_t cc = excl;
            for (int j = 3; j >= 0; --j) {    // walk bins descending
                cc += acc[j];
                if (cc >= k) {
                    bc[0] = (uint32_t)(base_bin + j);
                    bc[1] = k - (cc - acc[j]);  // in-bin rank, 1-based
                    break;
                }
            }
        }
        __syncthreads();
        const uint32_t b1 = bc[0], k2 = bc[1];
        __syncthreads();

        // ---- L2: flat coalesced stream of key slots; hist bits 9..0 ----
        for (int i = t; i < 1024; i += 256) h[i] = 0;
        __syncthreads();
        const uint32_t* keys0 = ws + OFF_KEYS + (size_t)row * BPR * LBUF;
        const uint32_t total_slots = BPR * LBUF;  // 28672
        for (uint32_t g = t; g < total_slots; g += 256) {
            uint32_t seg = g / (uint32_t)LBUF;
            uint32_t i = g - seg * (uint32_t)LBUF;
            if (i < cnts[seg]) {
                uint32_t u = keys0[g];
                if (((u >> 10) & 0x3FFu) == b1) atomicAdd(&h[u & 0x3FFu], 1u);
            }
        }
        __syncthreads();
        {
            int hi = 1023 - t * 4;
            uint32_t s = 0;
            for (int j = 0; j < 4; ++j) s += h[hi - j];
            sc[t] = s;
            __syncthreads();
            for (int off = 1; off < 256; off <<= 1) {
                uint32_t v = (t >= off) ? sc[t - off] : 0u;
                __syncthreads();
                sc[t] += v;
                __syncthreads();
            }
            uint32_t excl2 = sc[t] - s;
            if (excl2 < k2 && excl2 + s >= k2) {
                uint32_t cc = excl2;
                for (int j = 0; j < 4; ++j) {
                    int bin = hi - j;
                    uint32_t hb = h[bin];
                    cc += hb;
                    if (cc >= k2) {
                        ws[OFF_THR + row] = (PRED_B << 20) | (b1 << 10) | (uint32_t)bin;
                        break;
                    }
                }
            }
        }
        return;
    }

    // ---- exact fallback: 4-pass 1024-bin select over the row (10+10+10+2) ----
    const uint4* px = (const uint4*)(x + (size_t)row * D);
    // Pass A: top 10 bits
    for (int i = t; i < 1024; i += 256) h[i] = 0;
    __syncthreads();
    for (int i = t; i < D / 4; i += 256) {
        uint4 v = px[i];
        atomicAdd(&h[mono(v.x) >> 22], 1u);
        atomicAdd(&h[mono(v.y) >> 22], 1u);
        atomicAdd(&h[mono(v.z) >> 22], 1u);
        atomicAdd(&h[mono(v.w) >> 22], 1u);
    }
    __syncthreads();
    {
        int hi = 1023 - t * 4;
        uint32_t s = 0;
        for (int j = 0; j < 4; ++j) s += h[hi - j];
        sc[t] = s;
        __syncthreads();
        for (int off = 1; off < 256; off <<= 1) {
            uint32_t v = (t >= off) ? sc[t - off] : 0u;
            __syncthreads();
            sc[t] += v;
            __syncthreads();
        }
        uint32_t excl = sc[t] - s;
        if (excl < KSEL && excl + s >= KSEL) {
            uint32_t cc = excl;
            for (int j = 0; j < 4; ++j) {
                int bin = hi - j;
                uint32_t hb = h[bin];
                cc += hb;
                if (cc >= KSEL) { bc[0] = (uint32_t)bin; bc[1] = KSEL - (cc - hb); break; }
            }
        }
    }
    __syncthreads();
    const uint32_t B10 = bc[0], r1 = bc[1];
    __syncthreads();
    // Pass B: bits 21..12 among top == B10
    for (int i = t; i < 1024; i += 256) h[i] = 0;
    __syncthreads();
    for (int i = t; i < D / 4; i += 256) {
        uint4 v = px[i];
        uint32_t u;
        u = mono(v.x); if ((u >> 22) == B10) atomicAdd(&h[(u >> 12) & 0x3FFu], 1u);
        u = mono(v.y); if ((u >> 22) == B10) atomicAdd(&h[(u >> 12) & 0x3FFu], 1u);
        u = mono(v.z); if ((u >> 22) == B10) atomicAdd(&h[(u >> 12) & 0x3FFu], 1u);
        u = mono(v.w); if ((u >> 22) == B10) atomicAdd(&h[(u >> 12) & 0x3FFu], 1u);
    }
    __syncthreads();
    {
        int hi = 1023 - t * 4;
        uint32_t s = 0;
        for (int j = 0; j < 4; ++j) s += h[hi - j];
        sc[t] = s;
        __syncthreads();
        for (int off = 1; off < 256; off <<= 1) {
            uint32_t v = (t >= off) ? sc[t - off] : 0u;
            __syncthreads();
            sc[t] += v;
            __syncthreads();
        }
        uint32_t excl = sc[t] - s;
        if (excl < r1 && excl + s >= r1) {
            uint32_t cc = excl;
            for (int j = 0; j < 4; ++j) {
                int bin = hi - j;
                uint32_t hb = h[bin];
                cc += hb;
                if (cc >= r1) { bc[0] = (uint32_t)bin; bc[1] = r1 - (cc - hb); break; }
            }
        }
    }
    __syncthreads();
    const uint32_t pref20 = (B10 << 10) | bc[0];
    const uint32_t r2 = bc[1];
    __syncthreads();
    // Pass C: bits 11..2 among (u>>12) == pref20
    for (int i = t; i < 1024; i += 256) h[i] = 0;
    __syncthreads();
    for (int i = t; i < D / 4; i += 256) {
        uint4 v = px[i];
        uint32_t u;
        u = mono(v.x); if ((u >> 12) == pref20) atomicAdd(&h[(u >> 2) & 0x3FFu], 1u);
        u = mono(v.y); if ((u >> 12) == pref20) atomicAdd(&h[(u >> 2) & 0x3FFu], 1u);
        u = mono(v.z); if ((u >> 12) == pref20) atomicAdd(&h[(u >> 2) & 0x3FFu], 1u);
        u = mono(v.w); if ((u >> 12) == pref20) atomicAdd(&h[(u >> 2) & 0x3FFu], 1u);
    }
    __syncthreads();
    {
        int hi = 1023 - t * 4;
        uint32_t s = 0;
        for (int j = 0; j < 4; ++j) s += h[hi - j];
        sc[t] = s;
        __syncthreads();
        for (int off = 1; off < 256; off <<= 1) {
            uint32_t v = (t >= off) ? sc[t - off] : 0u;
            __syncthreads();
            sc[t] += v;
            __syncthreads();
        }
        uint32_t excl = sc[t] - s;
        if (excl < r2 && excl + s >= r2) {
            uint32_t cc = excl;
            for (int j = 0; j < 4; ++j) {
                int bin = hi - j;
                uint32_t hb = h[bin];
                cc += hb;
                if (cc >= r2) { bc[0] = (pref20 << 10) | (uint32_t)bin; bc[1] = r2 - (cc - hb); break; }
            }
        }
    }
    __syncthreads();
    const uint32_t pref30 = bc[0];   // top 30 bits
    const uint32_t r3 = bc[1];
    __syncthreads();
    // Pass D: final 2 bits exactly
    if (t < 4) h[t] = 0;
    __syncthreads();
    for (int i = t; i < D / 4; i += 256) {
        uint4 v = px[i];
        uint32_t u;
        u = mono(v.x); if ((u >> 2) == pref30) atomicAdd(&h[u & 3u], 1u);
        u = mono(v.y); if ((u >> 2) == pref30) atomicAdd(&h[u & 3u], 1u);
        u = mono(v.z); if ((u >> 2) == pref30) atomicAdd(&h[u & 3u], 1u);
        u = mono(v.w); if ((u >> 2) == pref30) atomicAdd(&h[u & 3u], 1u);
    }
    __syncthreads();
    if (t == 0) {
        uint32_t cc = 0;
        for (int b = 3; b >= 0; --b) {
            cc += h[b];
            if (cc >= r3) { ws[OFF_THR + row] = (pref30 << 2) | (uint32_t)b; break; }
        }
    }
}

// Kernel 3: streaming masked copy, 8-deep MLP batch, NT stores.
__global__ __launch_bounds__(256) void mask_final(const uint32_t* __restrict__ x,
                                                  float* __restrict__ out,
                                                  const uint32_t* __restrict__ ws) {
    const int bid = blockIdx.x;                 // 4096 blocks
    const int row = bid / FBPR, chunk = bid % FBPR, t = threadIdx.x;
    const uint32_t tk = ws[OFF_THR + row];
    const uint4* __restrict__ p =
        (const uint4*)(x + (size_t)row * D) + (size_t)chunk * FCHUNK_V4;
    f32x4* __restrict__ o =
        (f32x4*)(out + (size_t)row * D) + (size_t)chunk * FCHUNK_V4;

    uint4 v[8];
#pragma unroll
    for (int k = 0; k < 8; ++k) v[k] = p[t + k * 256];   // 8 loads in flight
    f32x4 ov[8];
#pragma unroll
    for (int k = 0; k < 8; ++k) {
        ov[k][0] = (mono(v[k].x) < tk) ? __uint_as_float(v[k].x) : 0.0f;
        ov[k][1] = (mono(v[k].y) < tk) ? __uint_as_float(v[k].y) : 0.0f;
        ov[k][2] = (mono(v[k].z) < tk) ? __uint_as_float(v[k].z) : 0.0f;
        ov[k][3] = (mono(v[k].w) < tk) ? __uint_as_float(v[k].w) : 0.0f;
    }
#pragma unroll
    for (int k = 0; k < 8; ++k)
        __builtin_nontemporal_store(ov[k], &o[t + k * 256]);
}

extern "C" void kernel_launch(void* const* d_in, const int* in_sizes, int n_in,
                              void* d_out, int out_size, void* d_ws, size_t ws_size,
                              hipStream_t stream) {
    (void)in_sizes; (void)n_in; (void)out_size; (void)ws_size;
    const uint32_t* xu = (const uint32_t*)d_in[0];
    float* outp = (float*)d_out;
    uint32_t* ws = (uint32_t*)d_ws;

    cand_scan<<<ROWS * BPR, 256, 0, stream>>>(xu, ws);
    select_thr<<<ROWS, 256, 0, stream>>>(xu, ws);
    mask_final<<<ROWS * FBPR, 256, 0, stream>>>(xu, outp, ws);
}

// Round 21
// 88.587 us; speedup vs baseline: 7.1935x; 1.0785x over previous
//
#include <hip/hip_runtime.h>
#include <stdint.h>

// Problem constants
constexpr int ROWS = 64;
constexpr int D = 1 << 19;             // 524288 per row
constexpr uint32_t KSEL = 52428;       // int(0.1 * D)
constexpr int BPR = 32;                // blocks per row, cand_scan
constexpr int CHUNK = D / BPR;         // 16384 elements per block
constexpr int LBUF = 896;              // per-block key cap (expected ~352, +29 sigma)
constexpr uint32_t PRED_B = 0xBFAu;    // key bucket of floats [1.25, 1.375);
                                       // K-th largest = 1.2816 +- 0.0024 (13/39 sigma)

// mask_final geometry: 8 uint4 per thread, fully unrolled batch
constexpr int FBPR = 64;               // mask blocks per row
constexpr int FCHUNK_V4 = (D / 4) / FBPR;  // 2048 uint4 per block

// Workspace layout (u32 words) — ALL state plain-stored fresh every call
// before it is read (no accumulation, no zeroing, no cross-call state).
constexpr size_t OFF_SCNT  = 0;                        // [2048] per-block raw cand count
constexpr size_t OFF_ACNT  = 2048;                     // [2048] per-block above count
constexpr size_t OFF_THR   = 4096;                     // [64] threshold key per row
constexpr size_t OFF_BCNT  = 4160;                     // [2048][32] per-block sub-bucket counts
constexpr size_t OFF_CHIST = OFF_BCNT + 2048 * 32;     // [2048][512] u16-packed 1024-bin hist
constexpr size_t OFF_KEYS  = OFF_CHIST + 2048 * 512;   // [2048][LBUF] keys, bucketed by bits 19..15

typedef float f32x4 __attribute__((ext_vector_type(4)));

__device__ __forceinline__ uint32_t mono(uint32_t f) {
    uint32_t m = (uint32_t)((int32_t)f >> 31) | 0x80000000u;
    return f ^ m;
}

// Kernel 1 (read-only over x): candidate keys (bucket == PRED_B), stored
// SUB-BUCKETED by bits 19..15 (32 sub-buckets) + per-block sub-bucket
// counts + 1024-bin partial hist of bits 19..10 (packed u16) + above count.
__global__ __launch_bounds__(256) void cand_scan(const uint32_t* __restrict__ x,
                                                 uint32_t* __restrict__ ws) {
    __shared__ uint32_t lkey[LBUF];
    __shared__ uint32_t lkey2[LBUF];
    __shared__ uint32_t h1[1024];
    __shared__ uint32_t red[256];
    __shared__ uint32_t bcnt[32], bpre[32], boff[32];
    __shared__ uint32_t ln;
    for (int i = threadIdx.x; i < 1024; i += 256) h1[i] = 0;
    if (threadIdx.x < 32) { bcnt[threadIdx.x] = 0; boff[threadIdx.x] = 0; }
    if (threadIdx.x == 0) ln = 0;
    __syncthreads();
    const int bid = blockIdx.x;
    const int row = bid / BPR, chunk = bid % BPR, t = threadIdx.x;
    const uint4* __restrict__ p = (const uint4*)(x + (size_t)row * D + (size_t)chunk * CHUNK);
    uint32_t above = 0;
    for (int i = t; i < CHUNK / 4; i += 256) {
        uint4 v = p[i];
#define CLS(comp)                                                          \
        {                                                                  \
            uint32_t u = mono(comp);                                       \
            uint32_t bu = u >> 20;                                         \
            above += (bu > PRED_B);                                        \
            if (bu == PRED_B) {                                            \
                uint32_t s = atomicAdd(&ln, 1u);                           \
                if (s < (uint32_t)LBUF) lkey[s] = u;                       \
                atomicAdd(&h1[(u >> 10) & 0x3FFu], 1u);                    \
            }                                                              \
        }
        CLS(v.x) CLS(v.y) CLS(v.z) CLS(v.w)
#undef CLS
    }
    red[t] = above;
    __syncthreads();
    for (int off = 128; off > 0; off >>= 1) {
        if (t < off) red[t] += red[t + off];
        __syncthreads();
    }
    if (t == 0) {
        ws[OFF_SCNT + bid] = ln;       // raw count; > LBUF signals overflow
        ws[OFF_ACNT + bid] = red[0];
    }
    const uint32_t m = ln < (uint32_t)LBUF ? ln : (uint32_t)LBUF;
    // ---- epilogue: bucket keys by bits 19..15 (two cheap LDS passes) ----
    for (uint32_t i = t; i < m; i += 256) atomicAdd(&bcnt[(lkey[i] >> 15) & 31u], 1u);
    __syncthreads();
    if (t == 0) {
        uint32_t a = 0;
        for (int b = 0; b < 32; ++b) { bpre[b] = a; a += bcnt[b]; }
    }
    __syncthreads();
    for (uint32_t i = t; i < m; i += 256) {
        uint32_t u = lkey[i];
        uint32_t b = (u >> 15) & 31u;
        uint32_t pos = bpre[b] + atomicAdd(&boff[b], 1u);
        lkey2[pos] = u;
    }
    __syncthreads();
    if (t < 32) ws[OFF_BCNT + (size_t)bid * 32 + t] = bcnt[t];
    {
        uint32_t* ch = ws + OFF_CHIST + (size_t)bid * 512;
        for (int i = t; i < 512; i += 256)
            ch[i] = (h1[2 * i] & 0xFFFFu) | (h1[2 * i + 1] << 16);
    }
    uint32_t* sk = ws + OFF_KEYS + (size_t)bid * LBUF;
    for (uint32_t i = t; i < m; i += 256) sk[i] = lkey2[i];
}

// Kernel 2, one block per row: exact threshold key.
// L1: reduce the 32 packed hists -> b1 (bits 19..10) + in-bin rank k2.
// L2: read ONLY sub-bucket b1>>5 (~350 keys/row), filter ==b1, 1024-bin
// hist of low 10 bits -> exact thr_key. Fallback: 4-pass full-row select.
__global__ __launch_bounds__(256) void select_thr(const uint32_t* __restrict__ x,
                                                  uint32_t* __restrict__ ws) {
    __shared__ uint32_t h[1024];
    __shared__ uint32_t sc[256];
    __shared__ uint32_t segbase[BPR], segcnt[BPR];
    __shared__ uint32_t bc[2];
    const int row = blockIdx.x, t = threadIdx.x;

    // per-row totals (parallel)
    uint32_t myc = 0, mya = 0;
    if (t < BPR) {
        myc = ws[OFF_SCNT + (size_t)row * BPR + t];
        mya = ws[OFF_ACNT + (size_t)row * BPR + t];
    }
    sc[t] = (t < BPR) ? ((myc > (uint32_t)LBUF ? 0x40000000u : 0u) + myc) : 0u;
    __syncthreads();
    for (int off = 128; off > 0; off >>= 1) {
        if (t < off) sc[t] += sc[t + off];
        __syncthreads();
    }
    const uint32_t ntot_f = sc[0];
    __syncthreads();
    sc[t] = (t < BPR) ? mya : 0u;
    __syncthreads();
    for (int off = 128; off > 0; off >>= 1) {
        if (t < off) sc[t] += sc[t + off];
        __syncthreads();
    }
    const uint32_t above = sc[0];
    const uint32_t n = ntot_f & 0x3FFFFFFFu;
    const bool valid = ((ntot_f & 0xC0000000u) == 0u) &&
                       (above < KSEL) && (above + n >= KSEL);
    __syncthreads();

    if (valid) {
        const uint32_t k = KSEL - above;  // rank among candidates, 1-based

        // ---- L1: reduce packed per-block hists; descending ownership ----
        const int base_bin = 1020 - 4 * t;  // thread t owns bins [bb .. bb+3]
        uint32_t acc[4] = {0, 0, 0, 0};
        const uint32_t* ch0 = ws + OFF_CHIST + (size_t)row * BPR * 512 + (base_bin >> 1);
#pragma unroll 4
        for (int s = 0; s < BPR; ++s) {
            uint32_t p0 = ch0[(size_t)s * 512];
            uint32_t p1 = ch0[(size_t)s * 512 + 1];
            acc[0] += p0 & 0xFFFFu; acc[1] += p0 >> 16;
            acc[2] += p1 & 0xFFFFu; acc[3] += p1 >> 16;
        }
        uint32_t s_sum = acc[0] + acc[1] + acc[2] + acc[3];
        sc[t] = s_sum;
        __syncthreads();
        for (int off = 1; off < 256; off <<= 1) {
            uint32_t v = (t >= off) ? sc[t - off] : 0u;
            __syncthreads();
            sc[t] += v;
            __syncthreads();
        }
        uint32_t excl = sc[t] - s_sum;   // count in bins strictly above my group
        if (excl < k && excl + s_sum >= k) {  // exactly one thread
            uint32_t cc = excl;
            for (int j = 3; j >= 0; --j) {
                cc += acc[j];
                if (cc >= k) {
                    bc[0] = (uint32_t)(base_bin + j);
                    bc[1] = k - (cc - acc[j]);
                    break;
                }
            }
        }
        __syncthreads();
        const uint32_t b1 = bc[0], k2 = bc[1];
        __syncthreads();

        // ---- L2: read only sub-bucket b1>>5 across 32 segments ----
        const uint32_t sb = b1 >> 5;
        if (t < BPR) {
            const uint32_t* bc_ = ws + OFF_BCNT + ((size_t)row * BPR + t) * 32;
            uint32_t a = 0, c = 0;
            for (uint32_t b = 0; b < 32; ++b) {
                uint32_t v = bc_[b];
                if (b < sb) a += v;
                if (b == sb) c = v;
            }
            segbase[t] = a;
            segcnt[t] = c;
        }
        for (int i = t; i < 1024; i += 256) h[i] = 0;
        __syncthreads();
        const uint32_t* keys0 = ws + OFF_KEYS + (size_t)row * BPR * LBUF;
        for (int seg = 0; seg < BPR; ++seg) {
            uint32_t c = segcnt[seg];
            const uint32_t* sk = keys0 + (size_t)seg * LBUF + segbase[seg];
            for (uint32_t i = t; i < c; i += 256) {
                uint32_t u = sk[i];
                if (((u >> 10) & 0x3FFu) == b1) atomicAdd(&h[u & 0x3FFu], 1u);
            }
        }
        __syncthreads();
        {
            int hi = 1023 - t * 4;
            uint32_t s = 0;
            for (int j = 0; j < 4; ++j) s += h[hi - j];
            sc[t] = s;
            __syncthreads();
            for (int off = 1; off < 256; off <<= 1) {
                uint32_t v = (t >= off) ? sc[t - off] : 0u;
                __syncthreads();
                sc[t] += v;
                __syncthreads();
            }
            uint32_t excl2 = sc[t] - s;
            if (excl2 < k2 && excl2 + s >= k2) {
                uint32_t cc = excl2;
                for (int j = 0; j < 4; ++j) {
                    int bin = hi - j;
                    uint32_t hb = h[bin];
                    cc += hb;
                    if (cc >= k2) {
                        ws[OFF_THR + row] = (PRED_B << 20) | (b1 << 10) | (uint32_t)bin;
                        break;
                    }
                }
            }
        }
        return;
    }

    // ---- exact fallback: 4-pass 1024-bin select over the row (10+10+10+2) ----
    const uint4* px = (const uint4*)(x + (size_t)row * D);
    for (int i = t; i < 1024; i += 256) h[i] = 0;
    __syncthreads();
    for (int i = t; i < D / 4; i += 256) {
        uint4 v = px[i];
        atomicAdd(&h[mono(v.x) >> 22], 1u);
        atomicAdd(&h[mono(v.y) >> 22], 1u);
        atomicAdd(&h[mono(v.z) >> 22], 1u);
        atomicAdd(&h[mono(v.w) >> 22], 1u);
    }
    __syncthreads();
    {
        int hi = 1023 - t * 4;
        uint32_t s = 0;
        for (int j = 0; j < 4; ++j) s += h[hi - j];
        sc[t] = s;
        __syncthreads();
        for (int off = 1; off < 256; off <<= 1) {
            uint32_t v = (t >= off) ? sc[t - off] : 0u;
            __syncthreads();
            sc[t] += v;
            __syncthreads();
        }
        uint32_t excl = sc[t] - s;
        if (excl < KSEL && excl + s >= KSEL) {
            uint32_t cc = excl;
            for (int j = 0; j < 4; ++j) {
                int bin = hi - j;
                uint32_t hb = h[bin];
                cc += hb;
                if (cc >= KSEL) { bc[0] = (uint32_t)bin; bc[1] = KSEL - (cc - hb); break; }
            }
        }
    }
    __syncthreads();
    const uint32_t B10 = bc[0], r1 = bc[1];
    __syncthreads();
    for (int i = t; i < 1024; i += 256) h[i] = 0;
    __syncthreads();
    for (int i = t; i < D / 4; i += 256) {
        uint4 v = px[i];
        uint32_t u;
        u = mono(v.x); if ((u >> 22) == B10) atomicAdd(&h[(u >> 12) & 0x3FFu], 1u);
        u = mono(v.y); if ((u >> 22) == B10) atomicAdd(&h[(u >> 12) & 0x3FFu], 1u);
        u = mono(v.z); if ((u >> 22) == B10) atomicAdd(&h[(u >> 12) & 0x3FFu], 1u);
        u = mono(v.w); if ((u >> 22) == B10) atomicAdd(&h[(u >> 12) & 0x3FFu], 1u);
    }
    __syncthreads();
    {
        int hi = 1023 - t * 4;
        uint32_t s = 0;
        for (int j = 0; j < 4; ++j) s += h[hi - j];
        sc[t] = s;
        __syncthreads();
        for (int off = 1; off < 256; off <<= 1) {
            uint32_t v = (t >= off) ? sc[t - off] : 0u;
            __syncthreads();
            sc[t] += v;
            __syncthreads();
        }
        uint32_t excl = sc[t] - s;
        if (excl < r1 && excl + s >= r1) {
            uint32_t cc = excl;
            for (int j = 0; j < 4; ++j) {
                int bin = hi - j;
                uint32_t hb = h[bin];
                cc += hb;
                if (cc >= r1) { bc[0] = (uint32_t)bin; bc[1] = r1 - (cc - hb); break; }
            }
        }
    }
    __syncthreads();
    const uint32_t pref20 = (B10 << 10) | bc[0];
    const uint32_t r2 = bc[1];
    __syncthreads();
    for (int i = t; i < 1024; i += 256) h[i] = 0;
    __syncthreads();
    for (int i = t; i < D / 4; i += 256) {
        uint4 v = px[i];
        uint32_t u;
        u = mono(v.x); if ((u >> 12) == pref20) atomicAdd(&h[(u >> 2) & 0x3FFu], 1u);
        u = mono(v.y); if ((u >> 12) == pref20) atomicAdd(&h[(u >> 2) & 0x3FFu], 1u);
        u = mono(v.z); if ((u >> 12) == pref20) atomicAdd(&h[(u >> 2) & 0x3FFu], 1u);
        u = mono(v.w); if ((u >> 12) == pref20) atomicAdd(&h[(u >> 2) & 0x3FFu], 1u);
    }
    __syncthreads();
    {
        int hi = 1023 - t * 4;
        uint32_t s = 0;
        for (int j = 0; j < 4; ++j) s += h[hi - j];
        sc[t] = s;
        __syncthreads();
        for (int off = 1; off < 256; off <<= 1) {
            uint32_t v = (t >= off) ? sc[t - off] : 0u;
            __syncthreads();
            sc[t] += v;
            __syncthreads();
        }
        uint32_t excl = sc[t] - s;
        if (excl < r2 && excl + s >= r2) {
            uint32_t cc = excl;
            for (int j = 0; j < 4; ++j) {
                int bin = hi - j;
                uint32_t hb = h[bin];
                cc += hb;
                if (cc >= r2) { bc[0] = (pref20 << 10) | (uint32_t)bin; bc[1] = r2 - (cc - hb); break; }
            }
        }
    }
    __syncthreads();
    const uint32_t pref30 = bc[0];
    const uint32_t r3 = bc[1];
    __syncthreads();
    if (t < 4) h[t] = 0;
    __syncthreads();
    for (int i = t; i < D / 4; i += 256) {
        uint4 v = px[i];
        uint32_t u;
        u = mono(v.x); if ((u >> 2) == pref30) atomicAdd(&h[u & 3u], 1u);
        u = mono(v.y); if ((u >> 2) == pref30) atomicAdd(&h[u & 3u], 1u);
        u = mono(v.z); if ((u >> 2) == pref30) atomicAdd(&h[u & 3u], 1u);
        u = mono(v.w); if ((u >> 2) == pref30) atomicAdd(&h[u & 3u], 1u);
    }
    __syncthreads();
    if (t == 0) {
        uint32_t cc = 0;
        for (int b = 3; b >= 0; --b) {
            cc += h[b];
            if (cc >= r3) { ws[OFF_THR + row] = (pref30 << 2) | (uint32_t)b; break; }
        }
    }
}

// Kernel 3: streaming masked copy, 8-deep MLP batch, NT stores.
__global__ __launch_bounds__(256) void mask_final(const uint32_t* __restrict__ x,
                                                  float* __restrict__ out,
                                                  const uint32_t* __restrict__ ws) {
    const int bid = blockIdx.x;                 // 4096 blocks
    const int row = bid / FBPR, chunk = bid % FBPR, t = threadIdx.x;
    const uint32_t tk = ws[OFF_THR + row];
    const uint4* __restrict__ p =
        (const uint4*)(x + (size_t)row * D) + (size_t)chunk * FCHUNK_V4;
    f32x4* __restrict__ o =
        (f32x4*)(out + (size_t)row * D) + (size_t)chunk * FCHUNK_V4;

    uint4 v[8];
#pragma unroll
    for (int k = 0; k < 8; ++k) v[k] = p[t + k * 256];   // 8 loads in flight
    f32x4 ov[8];
#pragma unroll
    for (int k = 0; k < 8; ++k) {
        ov[k][0] = (mono(v[k].x) < tk) ? __uint_as_float(v[k].x) : 0.0f;
        ov[k][1] = (mono(v[k].y) < tk) ? __uint_as_float(v[k].y) : 0.0f;
        ov[k][2] = (mono(v[k].z) < tk) ? __uint_as_float(v[k].z) : 0.0f;
        ov[k][3] = (mono(v[k].w) < tk) ? __uint_as_float(v[k].w) : 0.0f;
    }
#pragma unroll
    for (int k = 0; k < 8; ++k)
        __builtin_nontemporal_store(ov[k], &o[t + k * 256]);
}

extern "C" void kernel_launch(void* const* d_in, const int* in_sizes, int n_in,
                              void* d_out, int out_size, void* d_ws, size_t ws_size,
                              hipStream_t stream) {
    (void)in_sizes; (void)n_in; (void)out_size; (void)ws_size;
    const uint32_t* xu = (const uint32_t*)d_in[0];
    float* outp = (float*)d_out;
    uint32_t* ws = (uint32_t*)d_ws;

    cand_scan<<<ROWS * BPR, 256, 0, stream>>>(xu, ws);
    select_thr<<<ROWS, 256, 0, stream>>>(xu, ws);
    mask_final<<<ROWS * FBPR, 256, 0, stream>>>(xu, outp, ws);
}